// Round 1
// baseline (165.053 us; speedup 1.0000x reference)
//
#include <hip/hip_runtime.h>

// Shapes are fixed by the reference: B=4, N=384 (=M), D=256.
#define DD 256
#define NN 384
#define BB 4
#define BN (BB * NN) // 1536

// tanh(s) = 1 - 2/(exp2(2*log2e*s)+1). Pre-scale K by 2*log2e; mask adds
// -1e9*2*log2e in the exp2 domain -> exp2 -> 0 -> rcp(1)=1 -> contrib = -v,
// which equals tanh(-1e9+eps) = -1 exactly.
constexpr float TWO_LOG2E = 2.8853900817779268f;
constexpr float MASK_X    = -1.0e9f * 2.8853900817779268f;

// ---------------------------------------------------------------------------
// Kernel 1: the three projections. grid = (BN/8, 3), block = 256 (tid = d).
//   y=0: Q   = q@Wq + bq              -> Qout  (planar, stride 1)
//   y=1: K'  = (k@Wk + bk)*2log2e     -> KVout (.x of float2)
//   y=2: V   = v@Wv + bv              -> KVout (.y of float2)
// 8 rows/block amortizes the 256 KB W read (L2-resident).
// ---------------------------------------------------------------------------
__global__ __launch_bounds__(256) void proj_kernel(
    const float* __restrict__ q,  const float* __restrict__ k,  const float* __restrict__ v,
    const float* __restrict__ Wq, const float* __restrict__ Wk, const float* __restrict__ Wv,
    const float* __restrict__ bq, const float* __restrict__ bk, const float* __restrict__ bv,
    float* __restrict__ Qout, float* __restrict__ KVout)
{
    const int tid  = threadIdx.x;
    const int row0 = blockIdx.x * 8;
    const int which = blockIdx.y;

    const float* X; const float* W; const float* bias; float scale; float* out; int ostride;
    if (which == 0)      { X = q; W = Wq; bias = bq; scale = 1.0f;      out = Qout;      ostride = 1; }
    else if (which == 1) { X = k; W = Wk; bias = bk; scale = TWO_LOG2E; out = KVout;     ostride = 2; }
    else                 { X = v; W = Wv; bias = bv; scale = 1.0f;      out = KVout + 1; ostride = 2; }

    __shared__ float xs[8][DD];
    #pragma unroll
    for (int r = 0; r < 8; ++r)
        xs[r][tid] = X[(row0 + r) * DD + tid];
    __syncthreads();

    float acc[8] = {0.f,0.f,0.f,0.f,0.f,0.f,0.f,0.f};
    for (int k0 = 0; k0 < DD; k0 += 4) {
        const float w0 = W[(k0 + 0) * DD + tid];
        const float w1 = W[(k0 + 1) * DD + tid];
        const float w2 = W[(k0 + 2) * DD + tid];
        const float w3 = W[(k0 + 3) * DD + tid];
        #pragma unroll
        for (int r = 0; r < 8; ++r) {
            const float4 x4 = *reinterpret_cast<const float4*>(&xs[r][k0]); // broadcast ds_read_b128
            acc[r] = fmaf(x4.x, w0, acc[r]);
            acc[r] = fmaf(x4.y, w1, acc[r]);
            acc[r] = fmaf(x4.z, w2, acc[r]);
            acc[r] = fmaf(x4.w, w3, acc[r]);
        }
    }
    const float bb = bias[tid];
    #pragma unroll
    for (int r = 0; r < 8; ++r)
        out[((row0 + r) * DD + tid) * ostride] = (acc[r] + bb) * scale;
}

// ---------------------------------------------------------------------------
// Kernel 2: out[b,n,d] = sum_m tanh(Q*K' + maskX) * V.
// grid = (NN/4, BB), block = 256 (tid = d). 4 n-rows per block: Q in regs,
// mask tile in LDS as additive exp2-domain floats, [m][j] layout for b128.
// ---------------------------------------------------------------------------
__global__ __launch_bounds__(256) void mhsa_kernel(
    const float* __restrict__ Q, const float* __restrict__ KV,
    const int* __restrict__ mask, float* __restrict__ out)
{
    const int tid = threadIdx.x;         // d
    const int b   = blockIdx.y;
    const int n0  = blockIdx.x * 4;

    __shared__ float mf[NN * 4];         // [m][j], 6 KB
    for (int idx = tid; idx < NN * 4; idx += 256) {
        const int j = idx & 3;
        const int m = idx >> 2;
        mf[idx] = mask[(b * NN + (n0 + j)) * NN + m] ? MASK_X : 0.0f;
    }
    __syncthreads();

    float qv[4];
    #pragma unroll
    for (int j = 0; j < 4; ++j)
        qv[j] = Q[(b * NN + n0 + j) * DD + tid];

    const float2* kvp = reinterpret_cast<const float2*>(KV) + (size_t)b * NN * DD + tid;

    float acc[4] = {0.f, 0.f, 0.f, 0.f};
    #pragma unroll 2
    for (int m = 0; m < NN; ++m) {
        const float2 kv = kvp[(size_t)m * DD];                               // k' , v
        const float4 m4 = *reinterpret_cast<const float4*>(&mf[m * 4]);      // broadcast b128
        const float mfj[4] = {m4.x, m4.y, m4.z, m4.w};
        #pragma unroll
        for (int j = 0; j < 4; ++j) {
            const float x = fmaf(qv[j], kv.x, mfj[j]);   // 2log2e*(q*k - 1e9*mask)
            const float E = __builtin_amdgcn_exp2f(x);   // 0 on masked, inf ok
            const float r = __builtin_amdgcn_rcpf(E + 1.0f);
            const float t = kv.y * r;
            acc[j] += fmaf(-2.0f, t, kv.y);              // v*(1 - 2/(E+1)) = v*tanh
        }
    }
    #pragma unroll
    for (int j = 0; j < 4; ++j)
        out[(b * NN + n0 + j) * DD + tid] = acc[j];
}

extern "C" void kernel_launch(void* const* d_in, const int* in_sizes, int n_in,
                              void* d_out, int out_size, void* d_ws, size_t ws_size,
                              hipStream_t stream) {
    const float* q    = (const float*)d_in[0];
    const float* k    = (const float*)d_in[1];
    const float* v    = (const float*)d_in[2];
    const int*   mask = (const int*)  d_in[3];
    const float* Wq   = (const float*)d_in[4];
    const float* bq   = (const float*)d_in[5];
    const float* Wk   = (const float*)d_in[6];
    const float* bk   = (const float*)d_in[7];
    const float* Wv   = (const float*)d_in[8];
    const float* bv   = (const float*)d_in[9];
    float* out = (float*)d_out;

    float* Qws  = (float*)d_ws;          // BN*DD floats   (1.57 MB)
    float* KVws = Qws + (size_t)BN * DD; // BN*DD float2s  (3.14 MB)

    dim3 g1(BN / 8, 3);
    proj_kernel<<<g1, 256, 0, stream>>>(q, k, v, Wq, Wk, Wv, bq, bk, bv, Qws, KVws);

    dim3 g2(NN / 4, BB);
    mhsa_kernel<<<g2, 256, 0, stream>>>(Qws, KVws, mask, out);
}

// Round 2
// 130.853 us; speedup vs baseline: 1.2614x; 1.2614x over previous
//
#include <hip/hip_runtime.h>

// Shapes fixed by the reference: B=4, N=M=384, D=256.
#define DD 256
#define NN 384
#define BB 4
#define BN (BB * NN)       // 1536
#define MSPLIT 4
#define MCHUNK (NN / MSPLIT) // 96

// tanh(s) = 1 - 2/(exp2(2*log2e*s)+1). K pre-scaled by 2*log2e; mask adds
// -1e9*2log2e in exp2 domain -> E=0 -> rcp(1)=1 -> contribution -v = tanh(-inf)*v.
constexpr float TWO_LOG2E = 2.8853900817779268f;
constexpr float MASK_X    = -1.0e9f * 2.8853900817779268f;

// ---------------------------------------------------------------------------
// Projections: grid (BN/8, 3), block 256 (tid = d).
//  y=0: Q = q@Wq+bq -> Qout (planar); y=1: K' = (k@Wk+bk)*2log2e -> KV.x;
//  y=2: V = v@Wv+bv -> KV.y.  k-loop steps by 8 with explicit w[] prefetch
//  so 8-16 global loads stay in flight (R1 had VGPR=16, latency-bound).
// ---------------------------------------------------------------------------
__global__ __launch_bounds__(256) void proj_kernel(
    const float* __restrict__ q,  const float* __restrict__ k,  const float* __restrict__ v,
    const float* __restrict__ Wq, const float* __restrict__ Wk, const float* __restrict__ Wv,
    const float* __restrict__ bq, const float* __restrict__ bk, const float* __restrict__ bv,
    float* __restrict__ Qout, float* __restrict__ KVout)
{
    const int tid  = threadIdx.x;
    const int row0 = blockIdx.x * 8;
    const int which = blockIdx.y;

    const float* X; const float* W; const float* bias; float scale; float* out; int ostride;
    if (which == 0)      { X = q; W = Wq; bias = bq; scale = 1.0f;      out = Qout;      ostride = 1; }
    else if (which == 1) { X = k; W = Wk; bias = bk; scale = TWO_LOG2E; out = KVout;     ostride = 2; }
    else                 { X = v; W = Wv; bias = bv; scale = 1.0f;      out = KVout + 1; ostride = 2; }

    __shared__ float xs[8][DD];
    #pragma unroll
    for (int r = 0; r < 8; ++r)
        xs[r][tid] = X[(row0 + r) * DD + tid];
    __syncthreads();

    float acc[8] = {0.f,0.f,0.f,0.f,0.f,0.f,0.f,0.f};
    #pragma unroll 2
    for (int k0 = 0; k0 < DD; k0 += 8) {
        float w[8];
        #pragma unroll
        for (int j = 0; j < 8; ++j)
            w[j] = W[(k0 + j) * DD + tid];
        #pragma unroll
        for (int r = 0; r < 8; ++r) {
            const float4 xa = *reinterpret_cast<const float4*>(&xs[r][k0]);     // broadcast
            const float4 xb = *reinterpret_cast<const float4*>(&xs[r][k0 + 4]);
            acc[r] = fmaf(xa.x, w[0], acc[r]);
            acc[r] = fmaf(xa.y, w[1], acc[r]);
            acc[r] = fmaf(xa.z, w[2], acc[r]);
            acc[r] = fmaf(xa.w, w[3], acc[r]);
            acc[r] = fmaf(xb.x, w[4], acc[r]);
            acc[r] = fmaf(xb.y, w[5], acc[r]);
            acc[r] = fmaf(xb.z, w[6], acc[r]);
            acc[r] = fmaf(xb.w, w[7], acc[r]);
        }
    }
    const float bb = bias[tid];
    #pragma unroll
    for (int r = 0; r < 8; ++r)
        out[((row0 + r) * DD + tid) * ostride] = (acc[r] + bb) * scale;
}

// ---------------------------------------------------------------------------
// Fused tanh-contraction, m-split for occupancy: grid (NN/4, BB, MSPLIT),
// block 256 (tid = d). 1536 blocks = exactly 6/CU (R1: 384 blocks, 1.5/CU,
// 36% VALUBusy). Each block handles 96 m's; partials atomicAdd'ed onto a
// zeroed out. 8 KV float2 loads prefetched per group (x2 via unroll 2).
// ---------------------------------------------------------------------------
__global__ __launch_bounds__(256, 6) void mhsa_kernel(
    const float* __restrict__ Q, const float* __restrict__ KV,
    const int* __restrict__ mask, float* __restrict__ out)
{
    const int tid = threadIdx.x;         // d
    const int b   = blockIdx.y;
    const int n0  = blockIdx.x * 4;
    const int m0  = blockIdx.z * MCHUNK;

    __shared__ float mf[MCHUNK * 4];     // [m_local][j], 1.5 KB
    for (int idx = tid; idx < MCHUNK * 4; idx += 256) {
        const int m = idx % MCHUNK;      // consecutive tid -> consecutive m (coalesced)
        const int j = idx / MCHUNK;
        mf[m * 4 + j] = mask[(b * NN + n0 + j) * NN + (m0 + m)] ? MASK_X : 0.0f;
    }
    __syncthreads();

    float qv[4];
    #pragma unroll
    for (int j = 0; j < 4; ++j)
        qv[j] = Q[(b * NN + n0 + j) * DD + tid];

    const float2* kvp = reinterpret_cast<const float2*>(KV)
                      + (size_t)b * NN * DD + (size_t)m0 * DD + tid;

    float acc[4] = {0.f, 0.f, 0.f, 0.f};
    #pragma unroll 2
    for (int mg = 0; mg < MCHUNK; mg += 8) {
        float2 kv[8];
        #pragma unroll
        for (int u = 0; u < 8; ++u)
            kv[u] = kvp[(size_t)(mg + u) * DD];          // 8 independent L2 loads in flight
        #pragma unroll
        for (int u = 0; u < 8; ++u) {
            const float4 m4 = *reinterpret_cast<const float4*>(&mf[(mg + u) * 4]);
            const float mfj[4] = {m4.x, m4.y, m4.z, m4.w};
            #pragma unroll
            for (int j = 0; j < 4; ++j) {
                const float x = fmaf(qv[j], kv[u].x, mfj[j]); // 2log2e*(q*k) + mask
                const float E = __builtin_amdgcn_exp2f(x);    // 0 on masked, +inf ok
                const float r = __builtin_amdgcn_rcpf(E + 1.0f);
                acc[j] += fmaf(-2.0f * kv[u].y, r, kv[u].y);  // v*tanh
            }
        }
    }
    #pragma unroll
    for (int j = 0; j < 4; ++j)
        atomicAdd(&out[(b * NN + n0 + j) * DD + tid], acc[j]);
}

extern "C" void kernel_launch(void* const* d_in, const int* in_sizes, int n_in,
                              void* d_out, int out_size, void* d_ws, size_t ws_size,
                              hipStream_t stream) {
    const float* q    = (const float*)d_in[0];
    const float* k    = (const float*)d_in[1];
    const float* v    = (const float*)d_in[2];
    const int*   mask = (const int*)  d_in[3];
    const float* Wq   = (const float*)d_in[4];
    const float* bq   = (const float*)d_in[5];
    const float* Wk   = (const float*)d_in[6];
    const float* bk   = (const float*)d_in[7];
    const float* Wv   = (const float*)d_in[8];
    const float* bv   = (const float*)d_in[9];
    float* out = (float*)d_out;

    float* Qws  = (float*)d_ws;          // BN*DD floats   (1.57 MB)
    float* KVws = Qws + (size_t)BN * DD; // BN*DD float2s  (3.14 MB)

    // out receives atomic partials from MSPLIT chunks -> must start at 0.
    hipMemsetAsync(d_out, 0, (size_t)out_size * sizeof(float), stream);

    dim3 g1(BN / 8, 3);
    proj_kernel<<<g1, 256, 0, stream>>>(q, k, v, Wq, Wk, Wv, bq, bk, bv, Qws, KVws);

    dim3 g2(NN / 4, BB, MSPLIT);
    mhsa_kernel<<<g2, 256, 0, stream>>>(Qws, KVws, mask, out);
}